// Round 1
// baseline (99.619 us; speedup 1.0000x reference)
//
#include <hip/hip_runtime.h>
#include <math.h>

#define BATCH 128
#define FEAT  1024
#define CLS   500
#define HID   512
#define SPLITS 4

// ---------------------------------------------------------------------------
// Fused split-K GEMM for both halves:
//   imgP[z][m][n]  = sum_{k in split z} img[m][k]  * W1[n][k]        (m<128)
//   attrP[z][m][n] = sum_{k in split z} attr[m][k] * W1[n][FEAT+k]   (m<500)
// C = A * B^T with A (M,K) row-major, B rows of length ldb=2*FEAT.
// blockIdx.y < 2  -> img path;  else attr path (m-tile = blockIdx.y - 2).
// ---------------------------------------------------------------------------
constexpr int BM = 64, BN = 64, BK = 16;

__global__ __launch_bounds__(256) void gemm_bt_splitk(
    const float* __restrict__ img, const float* __restrict__ attr,
    const float* __restrict__ W1,
    float* __restrict__ imgP, float* __restrict__ attrP)
{
    __shared__ float As[BK][BM + 4];   // +4 words: keeps 16B align, 2-way banks
    __shared__ float Bs[BK][BN + 4];

    const int t  = threadIdx.x;
    const int z  = blockIdx.z;
    const int n0 = blockIdx.x * BN;

    const float* A;
    float* P;
    int M, boff, m0;
    if (blockIdx.y < 2) {              // image path: M=128 -> 2 m-tiles
        A = img;  P = imgP;  M = BATCH; boff = 0;
        m0 = blockIdx.y * BM;
    } else {                           // attribute path: M=500 -> 8 m-tiles
        A = attr; P = attrP; M = CLS;  boff = FEAT;
        m0 = (blockIdx.y - 2) * BM;
    }

    const int K   = FEAT;
    const int ldb = 2 * FEAT;
    const int Ks  = K / SPLITS;        // 256
    const int kbase = z * Ks;

    const int lrow = t >> 2;           // 0..63
    const int lk   = (t & 3) * 4;      // 0,4,8,12

    const int tn = t & 15;             // n micro index
    const int tm = t >> 4;             // m micro index

    float acc[4][4];
    #pragma unroll
    for (int i = 0; i < 4; ++i)
        #pragma unroll
        for (int j = 0; j < 4; ++j) acc[i][j] = 0.f;

    for (int kt = 0; kt < Ks; kt += BK) {
        // stage A tile (BM x BK) and B tile (BN x BK), transposed into LDS
        {
            const int m = m0 + lrow;
            float4 av = make_float4(0.f, 0.f, 0.f, 0.f);
            if (m < M)
                av = *(const float4*)&A[(size_t)m * K + kbase + kt + lk];
            As[lk + 0][lrow] = av.x;
            As[lk + 1][lrow] = av.y;
            As[lk + 2][lrow] = av.z;
            As[lk + 3][lrow] = av.w;

            const int n = n0 + lrow;   // N = 512, always in range
            const float4 bv =
                *(const float4*)&W1[(size_t)n * ldb + boff + kbase + kt + lk];
            Bs[lk + 0][lrow] = bv.x;
            Bs[lk + 1][lrow] = bv.y;
            Bs[lk + 2][lrow] = bv.z;
            Bs[lk + 3][lrow] = bv.w;
        }
        __syncthreads();
        #pragma unroll
        for (int k = 0; k < BK; ++k) {
            const float4 a = *(const float4*)&As[k][tm * 4];
            const float4 b = *(const float4*)&Bs[k][tn * 4];
            acc[0][0] = fmaf(a.x, b.x, acc[0][0]);
            acc[0][1] = fmaf(a.x, b.y, acc[0][1]);
            acc[0][2] = fmaf(a.x, b.z, acc[0][2]);
            acc[0][3] = fmaf(a.x, b.w, acc[0][3]);
            acc[1][0] = fmaf(a.y, b.x, acc[1][0]);
            acc[1][1] = fmaf(a.y, b.y, acc[1][1]);
            acc[1][2] = fmaf(a.y, b.z, acc[1][2]);
            acc[1][3] = fmaf(a.y, b.w, acc[1][3]);
            acc[2][0] = fmaf(a.z, b.x, acc[2][0]);
            acc[2][1] = fmaf(a.z, b.y, acc[2][1]);
            acc[2][2] = fmaf(a.z, b.z, acc[2][2]);
            acc[2][3] = fmaf(a.z, b.w, acc[2][3]);
            acc[3][0] = fmaf(a.w, b.x, acc[3][0]);
            acc[3][1] = fmaf(a.w, b.y, acc[3][1]);
            acc[3][2] = fmaf(a.w, b.z, acc[3][2]);
            acc[3][3] = fmaf(a.w, b.w, acc[3][3]);
        }
        __syncthreads();
    }

    float* Pz = P + (size_t)z * M * HID;
    #pragma unroll
    for (int i = 0; i < 4; ++i) {
        const int m = m0 + tm * 4 + i;
        if (m < M) {
            float4 v = make_float4(acc[i][0], acc[i][1], acc[i][2], acc[i][3]);
            *(float4*)&Pz[(size_t)m * HID + n0 + tn * 4] = v;
        }
    }
}

// ---------------------------------------------------------------------------
// Merge split-K partials; fold b1 into the image part.
// ---------------------------------------------------------------------------
__global__ __launch_bounds__(256) void merge_kernel(
    const float* __restrict__ imgP, const float* __restrict__ attrP,
    const float* __restrict__ b1,
    float* __restrict__ imgF, float* __restrict__ attrF)
{
    const int NIMG  = BATCH * HID;   // 65536
    const int NATTR = CLS * HID;     // 256000
    const int idx = blockIdx.x * 256 + threadIdx.x;
    if (idx < NIMG) {
        float s = 0.f;
        #pragma unroll
        for (int zz = 0; zz < SPLITS; ++zz) s += imgP[zz * NIMG + idx];
        imgF[idx] = s + b1[idx & (HID - 1)];
    } else if (idx < NIMG + NATTR) {
        const int j = idx - NIMG;
        float s = 0.f;
        #pragma unroll
        for (int zz = 0; zz < SPLITS; ++zz) s += attrP[zz * NATTR + j];
        attrF[j] = s;
    }
}

// ---------------------------------------------------------------------------
// Pair kernel: out[b,c] = sigmoid( sum_h relu(imgF[b,h]+attrF[c,h]) * W2[h] + b2 )
// 16x16 (b,c) tile per block, one pair per thread, h staged in LDS chunks.
// ---------------------------------------------------------------------------
constexpr int TB = 16, TC = 16, HC = 256;

__global__ __launch_bounds__(256) void pair_kernel(
    const float* __restrict__ imgF, const float* __restrict__ attrF,
    const float* __restrict__ W2, const float* __restrict__ b2,
    float* __restrict__ out)
{
    __shared__ float U[TB][HC + 4];
    __shared__ float V[TC][HC + 4];
    __shared__ float w2s[HID];

    const int t  = threadIdx.x;
    const int c0 = blockIdx.x * TC;
    const int b0 = blockIdx.y * TB;

    w2s[t]       = W2[t];
    w2s[t + 256] = W2[t + 256];

    const int ci = t & 15;
    const int bi = t >> 4;

    float acc = 0.f;
    for (int hc = 0; hc < HID; hc += HC) {
        __syncthreads();   // covers w2s on first iter, U/V reuse after
        #pragma unroll
        for (int rep = 0; rep < 4; ++rep) {
            const int e   = rep * 256 + t;        // 0..1023
            const int row = e >> 6;               // 0..15
            const int c4  = (e & 63) * 4;         // 0..252
            *(float4*)&U[row][c4] =
                *(const float4*)&imgF[(b0 + row) * HID + hc + c4];
            const int c = c0 + row;
            float4 v = make_float4(0.f, 0.f, 0.f, 0.f);
            if (c < CLS)
                v = *(const float4*)&attrF[c * HID + hc + c4];
            *(float4*)&V[row][c4] = v;
        }
        __syncthreads();
        #pragma unroll
        for (int h4 = 0; h4 < HC / 4; ++h4) {
            const float4 u = *(const float4*)&U[bi][h4 * 4];
            const float4 v = *(const float4*)&V[ci][h4 * 4];
            const float4 w = *(const float4*)&w2s[hc + h4 * 4];
            acc = fmaf(fmaxf(u.x + v.x, 0.f), w.x, acc);
            acc = fmaf(fmaxf(u.y + v.y, 0.f), w.y, acc);
            acc = fmaf(fmaxf(u.z + v.z, 0.f), w.z, acc);
            acc = fmaf(fmaxf(u.w + v.w, 0.f), w.w, acc);
        }
    }

    const int b = b0 + bi;
    const int c = c0 + ci;
    if (c < CLS) {
        const float x = acc + b2[0];
        out[b * CLS + c] = 1.f / (1.f + __expf(-x));
    }
}

// ---------------------------------------------------------------------------
extern "C" void kernel_launch(void* const* d_in, const int* in_sizes, int n_in,
                              void* d_out, int out_size, void* d_ws, size_t ws_size,
                              hipStream_t stream) {
    const float* img  = (const float*)d_in[0];   // (128, 1024)
    const float* attr = (const float*)d_in[1];   // (500, 1024)
    const float* W1   = (const float*)d_in[2];   // (512, 2048)
    const float* b1   = (const float*)d_in[3];   // (512,)
    const float* W2   = (const float*)d_in[4];   // (1, 512)
    const float* b2   = (const float*)d_in[5];   // (1,)
    float* out = (float*)d_out;                  // (128, 500)

    float* ws    = (float*)d_ws;
    float* imgP  = ws;                                   // 4*128*512
    float* attrP = imgP  + (size_t)SPLITS * BATCH * HID; // 4*500*512
    float* imgF  = attrP + (size_t)SPLITS * CLS * HID;   // 128*512
    float* attrF = imgF  + (size_t)BATCH * HID;          // 500*512

    // Stage 1: both GEMMs in one dispatch. n-tiles=8, m-tiles=2(img)+8(attr), splits=4
    dim3 ggrid(HID / BN, 2 + 8, SPLITS);                 // 320 blocks
    gemm_bt_splitk<<<ggrid, 256, 0, stream>>>(img, attr, W1, imgP, attrP);

    // Stage 2: merge partials (+b1 on img side)
    const int ntot = BATCH * HID + CLS * HID;            // 321536
    merge_kernel<<<(ntot + 255) / 256, 256, 0, stream>>>(imgP, attrP, b1, imgF, attrF);

    // Stage 3: pair reduction + sigmoid
    dim3 pgrid((CLS + TC - 1) / TC, BATCH / TB);         // 32 x 8 = 256 blocks
    pair_kernel<<<pgrid, 256, 0, stream>>>(imgF, attrF, W2, b2, out);
}